// Round 13
// baseline (335.897 us; speedup 1.0000x reference)
//
#include <hip/hip_runtime.h>

#define T_LEN   16384
#define B_SZ    4
#define AUDIO_C 256
#define RES_C   64
#define SKIP_C  256
#define L_LAYERS 20

typedef unsigned short u16;
using bf16x8 = __attribute__((ext_vector_type(8))) __bf16;
using f32x4  = __attribute__((ext_vector_type(4))) float;

__device__ __forceinline__ u16 f2bf(float x){
    union { float f; unsigned u; } v; v.f = x;
    return (u16)((v.u + 0x7FFFu + ((v.u >> 16) & 1u)) >> 16);
}
// compiler-fused v_cvt_pk_bf16_f32 (a -> low 16, b -> high 16)
__device__ __forceinline__ unsigned cvt2(float a, float b){
    union { __bf16 h[2]; unsigned u; } r;
    r.h[0] = (__bf16)a; r.h[1] = (__bf16)b;
    return r.u;
}
__device__ __forceinline__ float bflo(unsigned u){ union{unsigned q; float f;} v; v.q = u << 16; return v.f; }
__device__ __forceinline__ float bfhi(unsigned u){ union{unsigned q; float f;} v; v.q = u & 0xffff0000u; return v.f; }
__device__ __forceinline__ f32x4 mfma16(uint4 a, uint4 b, f32x4 c){
    return __builtin_amdgcn_mfma_f32_16x16x32_bf16(
        __builtin_bit_cast(bf16x8, a), __builtin_bit_cast(bf16x8, b), c, 0, 0, 0);
}
// XCD-aware bijective swizzles
__device__ __forceinline__ int xcd_swz1k(int bid){ return (bid & 7) * 128 + (bid >> 3); }
__device__ __forceinline__ int xcd_swz512(int bid){ return (bid & 7) * 64 + (bid >> 3); }
// raw barrier: LDS visibility only — VMEM loads stay in flight (no vmcnt(0) drain)
__device__ __forceinline__ void bar_lgkm(){
    asm volatile("s_waitcnt lgkmcnt(0)" ::: "memory");
    __builtin_amdgcn_s_barrier();
    asm volatile("" ::: "memory");
}

// ================= repack: weights -> per-lane MFMA A-fragments (bf16) =================
__global__ __launch_bounds__(256) void repack2(
    const float* __restrict__ fw, const float* __restrict__ gw,
    const float* __restrict__ sw, const float* __restrict__ rw,
    const float* __restrict__ p1, const float* __restrict__ p2,
    const float* __restrict__ prw, const float* __restrict__ sb,
    u16* __restrict__ w1p, u16* __restrict__ swp, u16* __restrict__ rwp,
    u16* __restrict__ pp1p, u16* __restrict__ pp2p,
    u16* __restrict__ prep, float* __restrict__ sbsum)
{
    int idx = blockIdx.x * 256 + threadIdx.x;
    if (idx < 327680) {                             // w1p: GEMM1 A, K=128
        int j = idx & 7, l = (idx >> 3) & 63, kk = (idx >> 9) & 3, mt = (idx >> 11) & 7, i = idx >> 14;
        int m = mt * 16 + (l & 15);
        int k = kk * 32 + (l >> 4) * 8 + j;
        const float* srcw = (m < 64) ? fw : gw;
        int mm = m & 63, c = k & 63, tap = k >> 6;
        w1p[idx] = f2bf(srcw[((i * 64 + mm) * 64 + c) * 2 + tap]);
        return;
    }
    idx -= 327680;
    if (idx < 327680) {                             // swp: skip A, K=64
        int j = idx & 7, l = (idx >> 3) & 63, kk = (idx >> 9) & 1, mt = (idx >> 10) & 15, i = idx >> 14;
        int p = mt * 16 + (l & 15);
        int c = kk * 32 + (l >> 4) * 8 + j;
        swp[idx] = f2bf(sw[(i * 256 + p) * 64 + c]);
        return;
    }
    idx -= 327680;
    if (idx < 81920) {                              // rwp: res A, K=64
        int j = idx & 7, l = (idx >> 3) & 63, kk = (idx >> 9) & 1, mt = (idx >> 10) & 3, i = idx >> 12;
        int o = mt * 16 + (l & 15);
        int c = kk * 32 + (l >> 4) * 8 + j;
        rwp[idx] = f2bf(rw[(i * 64 + o) * 64 + c]);
        return;
    }
    idx -= 81920;
    if (idx < 65536) {                              // pp1p: K=256
        int j = idx & 7, l = (idx >> 3) & 63, kk = (idx >> 9) & 7, mt = idx >> 12;
        int m = mt * 16 + (l & 15);
        int k = kk * 32 + (l >> 4) * 8 + j;
        pp1p[idx] = f2bf(p1[m * 256 + k]);
        return;
    }
    idx -= 65536;
    if (idx < 65536) {                              // pp2p: K=256
        int j = idx & 7, l = (idx >> 3) & 63, kk = (idx >> 9) & 7, mt = idx >> 12;
        int m = mt * 16 + (l & 15);
        int k = kk * 32 + (l >> 4) * 8 + j;
        pp2p[idx] = f2bf(p2[m * 256 + k]);
        return;
    }
    idx -= 65536;
    if (idx < 16384) {                              // prep: pre A, M=64, K=256
        int j = idx & 7, l = (idx >> 3) & 63, kk = (idx >> 9) & 7, mt = idx >> 12;
        int m = mt * 16 + (l & 15);
        int k = kk * 32 + (l >> 4) * 8 + j;
        prep[idx] = f2bf(prw[m * 256 + k]);
        return;
    }
    idx -= 16384;
    if (idx < 256) {                                // sbsum[p] = sum_i skip_b[i][p]
        float s = 0.f;
        for (int i = 0; i < L_LAYERS; ++i) s += sb[i * 256 + idx];
        sbsum[idx] = s;
        return;
    }
}

// ================= pre (MFMA): ht[b][t][o] (bf16) = pre_w @ x + pre_b ==================
__global__ __launch_bounds__(256) void pre_mfma(
    const float* __restrict__ x, const u16* __restrict__ prep,
    const float* __restrict__ pre_b, u16* __restrict__ ht)
{
    __shared__ u16 sx[64 * 256];                    // 32 KB
    unsigned* sx32 = (unsigned*)sx;
    int tid = threadIdx.x;
    int w = tid >> 6, l = tid & 63;
    int lo = l & 15, hi = l >> 4;
    int wg = xcd_swz1k(blockIdx.x);
    int b = wg >> 8, t0 = (wg & 255) * 64;

    // weight fragments issued first (stay in flight across the raw barrier)
    const uint4* av = (const uint4*)prep;
    uint4 a[8];
#pragma unroll
    for (int kk = 0; kk < 8; ++kk) a[kk] = av[(w * 8 + kk) * 64 + l];

    {
        int t = l;
        const float* xb = x + (size_t)b * AUDIO_C * T_LEN + t0 + t;
#pragma unroll 8
        for (int c2 = 0; c2 < 64; c2 += 2) {
            int c = w * 64 + c2;
            float v0 = xb[(size_t)c * T_LEN];
            float v1 = xb[(size_t)(c + 1) * T_LEN];
            int ch = c >> 3;
            int a32 = t * 128 + ((ch ^ (t & 7)) << 2) + ((c >> 1) & 3);
            sx32[a32] = cvt2(v0, v1);
        }
    }
    bar_lgkm();

    f32x4 acc[4];
    {
        f32x4 ib;
#pragma unroll
        for (int r = 0; r < 4; ++r) ib[r] = pre_b[w * 16 + hi * 4 + r];
#pragma unroll
        for (int nt = 0; nt < 4; ++nt) acc[nt] = ib;
    }
#pragma unroll
    for (int kk = 0; kk < 8; ++kk) {
#pragma unroll
        for (int nt = 0; nt < 4; ++nt) {
            int t = nt * 16 + lo;
            int ch = kk * 4 + hi;
            uint4 bv = *(const uint4*)&sx32[t * 128 + ((ch ^ (t & 7)) << 2)];
            acc[nt] = mfma16(a[kk], bv, acc[nt]);
        }
    }
#pragma unroll
    for (int nt = 0; nt < 4; ++nt) {
        int t = t0 + nt * 16 + lo;
        uint2 ov;
        ov.x = cvt2(acc[nt][0], acc[nt][1]);
        ov.y = cvt2(acc[nt][2], acc[nt][3]);
        *(uint2*)(ht + ((size_t)b * T_LEN + t) * 64 + w * 16 + hi * 4) = ov;
    }
}

// ========== fused gated layer (t64/grid1024; h bf16 t-major; epilogue h from LDS) =========
template<int DO_SKIP>
__global__ __launch_bounds__(256) void layer_mfma(
    const u16* __restrict__ htin, u16* __restrict__ htout,
    u16* __restrict__ zTi, float* __restrict__ skipsum,
    const u16* __restrict__ w1p, const u16* __restrict__ swp, const u16* __restrict__ rwp,
    const float* __restrict__ fb, const float* __restrict__ gb,
    const float* __restrict__ sb, const float* __restrict__ rb,
    int d, int first, int last)
{
    __shared__ u16 hl[2 * 64 * 64];   // region0 = tap t-d, region1 = tap t (bf16)
    __shared__ u16 zl[64 * 64];       // 8 KB
    int tid = threadIdx.x;
    int w = tid >> 6, l = tid & 63;
    int lo = l & 15, hi = l >> 4;
    int wg = xcd_swz1k(blockIdx.x);
    int b = wg >> 8, t0 = (wg & 255) * 64;
    const u16* hb = htin + (size_t)b * T_LEN * 64;

    // ---- stage both taps (pure bf16 copy, no conversion): 1024 chunks, 4/thread ----
#pragma unroll
    for (int k = 0; k < 4; ++k) {
        int id = tid + k * 256;
        int region = id >> 9;             // 0 = tap t-d, 1 = tap t
        int row = (id >> 3) & 63;
        int g = id & 7;                   // 16B granule (8 channels)
        int t = region ? (t0 + row) : (t0 - d + row);
        uint4 bv = make_uint4(0u, 0u, 0u, 0u);
        if (t >= 0) bv = *(const uint4*)(hb + (size_t)t * 64 + g * 8);
        *(uint4*)(&hl[(region << 12) + row * 64 + ((g ^ (row & 7)) << 3)]) = bv;
    }

    // ---- weight fragments (L2) issued while stage is in flight ----
    const uint4* w1v = (const uint4*)w1p;
    uint4 aF[4], aG[4];
#pragma unroll
    for (int kk = 0; kk < 4; ++kk) {
        aF[kk] = w1v[(w * 4 + kk) * 64 + l];
        aG[kk] = w1v[((w + 4) * 4 + kk) * 64 + l];
    }
    uint4 aR[2];
    if (!last) {
        const uint4* rwv = (const uint4*)rwp;
        aR[0] = rwv[(w * 2 + 0) * 64 + l];
        aR[1] = rwv[(w * 2 + 1) * 64 + l];
    }
    f32x4 accF[4], accG[4];
    {
        f32x4 iF, iG;
#pragma unroll
        for (int r = 0; r < 4; ++r) { iF[r] = fb[w * 16 + hi * 4 + r]; iG[r] = gb[w * 16 + hi * 4 + r]; }
#pragma unroll
        for (int nt = 0; nt < 4; ++nt) { accF[nt] = iF; accG[nt] = iG; }
    }
    bar_lgkm();               // weight/VMEM loads NOT drained

    // ---- phase 1: GEMM1 from LDS (kk0,1 -> tap t-d; kk2,3 -> tap t) ----
    __builtin_amdgcn_s_setprio(1);
#pragma unroll
    for (int nt = 0; nt < 4; ++nt) {
        int n = nt * 16 + lo;
#pragma unroll
        for (int kk = 0; kk < 4; ++kk) {
            int gq = (kk & 1) * 4 + hi;
            uint4 bv = *(const uint4*)(&hl[(kk >> 1) * 4096 + n * 64 + ((gq ^ (n & 7)) << 3)]);
            accF[nt] = mfma16(aF[kk], bv, accF[nt]);
            accG[nt] = mfma16(aG[kk], bv, accG[nt]);
        }
    }
    __builtin_amdgcn_s_setprio(0);

    // ---- activation + z staging (LDS only) ----
#pragma unroll
    for (int nt = 0; nt < 4; ++nt) {
        float zv[4];
#pragma unroll
        for (int r = 0; r < 4; ++r) {
            float f = accF[nt][r], g = accG[nt][r];
            float ef = __expf(2.f * f);
            float th = 1.f - 2.f * __builtin_amdgcn_rcpf(ef + 1.f);
            float sg = __builtin_amdgcn_rcpf(1.f + __expf(-g));
            zv[r] = th * sg;
        }
        int n = nt * 16 + lo;
        int k0 = w * 16 + hi * 4;
        int col = k0 ^ ((n & 7) << 3);
        *(unsigned*)(&zl[n * 64 + col]) = cvt2(zv[0], zv[1]);
        *(unsigned*)(&zl[n * 64 + col + 2]) = cvt2(zv[2], zv[3]);
    }
    bar_lgkm();

    // ---- bulk coalesced z write: fire-and-forget under phase-2 MFMAs ----
    if (!DO_SKIP) {
#pragma unroll
        for (int q = 0; q < 2; ++q) {
            int idx = tid + q * 256;          // 512 chunks of 16B
            int row = idx >> 3, s = idx & 7;
            uint4 v = *(const uint4*)(&zl[row * 64 + ((s ^ (row & 7)) << 3)]);
            *(uint4*)(zTi + ((size_t)b * T_LEN + t0 + row) * 64 + s * 8) = v;
        }
    }

    // ---- phase 2: res GEMM (+ skip GEMM for plan C) ----
    uint4 aS[4][2];
    f32x4 accS[4][4];
    if (DO_SKIP) {
        const uint4* swv = (const uint4*)swp;
#pragma unroll
        for (int mi = 0; mi < 4; ++mi) {
            aS[mi][0] = swv[((w * 4 + mi) * 2 + 0) * 64 + l];
            aS[mi][1] = swv[((w * 4 + mi) * 2 + 1) * 64 + l];
            f32x4 iS;
#pragma unroll
            for (int r = 0; r < 4; ++r) iS[r] = sb[(w * 4 + mi) * 16 + hi * 4 + r];
#pragma unroll
            for (int nt = 0; nt < 4; ++nt) accS[mi][nt] = iS;
        }
    }
    f32x4 accR[4];
    if (!last) {
        f32x4 iR;
#pragma unroll
        for (int r = 0; r < 4; ++r) iR[r] = rb[w * 16 + hi * 4 + r];
#pragma unroll
        for (int nt = 0; nt < 4; ++nt) accR[nt] = iR;
    }
    __builtin_amdgcn_s_setprio(1);
#pragma unroll
    for (int nt = 0; nt < 4; ++nt) {
        int n = nt * 16 + lo;
#pragma unroll
        for (int kk = 0; kk < 2; ++kk) {
            int kb = kk * 32 + hi * 8;
            uint4 bz = *(const uint4*)(&zl[n * 64 + (kb ^ ((n & 7) << 3))]);
            if (!last) accR[nt] = mfma16(aR[kk], bz, accR[nt]);
            if (DO_SKIP) {
#pragma unroll
                for (int mi = 0; mi < 4; ++mi)
                    accS[mi][nt] = mfma16(aS[mi][kk], bz, accS[mi][nt]);
            }
        }
    }
    __builtin_amdgcn_s_setprio(0);

    // ---- epilogue: h_out = h_in(bf16, from LDS region 1) + res ----
    if (!last) {
        int ch = w * 2 + (hi >> 1);
        int halfo = (hi & 1) * 4;             // u16 offset within 16B chunk
#pragma unroll
        for (int nt = 0; nt < 4; ++nt) {
            int n = nt * 16 + lo;
            uint2 hp = *(const uint2*)(&hl[4096 + n * 64 + ((ch ^ (n & 7)) << 3) + halfo]);
            float o0 = bflo(hp.x) + accR[nt][0];
            float o1 = bfhi(hp.x) + accR[nt][1];
            float o2 = bflo(hp.y) + accR[nt][2];
            float o3 = bfhi(hp.y) + accR[nt][3];
            uint2 ov;
            ov.x = cvt2(o0, o1);
            ov.y = cvt2(o2, o3);
            int t = t0 + n;
            *(uint2*)(htout + ((size_t)b * T_LEN + t) * 64 + w * 16 + hi * 4) = ov;
        }
    }
    if (DO_SKIP) {
#pragma unroll
        for (int mi = 0; mi < 4; ++mi) {
#pragma unroll
            for (int nt = 0; nt < 4; ++nt) {
                int t = t0 + nt * 16 + lo;
                int p0 = (w * 4 + mi) * 16 + hi * 4;
#pragma unroll
                for (int r = 0; r < 4; ++r) {
                    float* sp = &skipsum[((size_t)b * 256 + p0 + r) * T_LEN + t];
                    float v = accS[mi][nt][r];
                    if (first) *sp = v; else *sp = *sp + v;
                }
            }
        }
    }
}

// ==== fused skip-reduce + pp1 + pp2 (t128/grid512: big bodies amortize per-body stall) ====
// 20 bodies; per body 64 MFMA/wave. 3-deep z prefetch (4 chunks/thread, 2 named slot sets).
#define SPX(L, CUR, OTH, RS)                                                     \
    {                                                                            \
        if ((L) + 1 < L_LAYERS) {                                                \
            u16* zn_ = lds + ((OTH) << 13);                                      \
            _Pragma("unroll")                                                    \
            for (int j = 0; j < 4; ++j)                                          \
                *(uint4*)(&zn_[loff[j]]) = RS[j];                                \
            if ((L) + 3 < L_LAYERS) {                                            \
                const u16* zs_ = zT + ((size_t)(((L) + 3) * 4 + b)) * T_LEN * 64;\
                _Pragma("unroll")                                                \
                for (int j = 0; j < 4; ++j)                                      \
                    RS[j] = *(const uint4*)(zs_ + goff[j]);                      \
            }                                                                    \
        }                                                                        \
        uint4 a1_[4];                                                            \
        _Pragma("unroll")                                                        \
        for (int mi = 0; mi < 4; ++mi)                                           \
            a1_[mi] = swv[(((L) * 16 + w * 4 + mi) * 2 + 1) * 64 + l];           \
        const u16* zc_ = lds + ((CUR) << 13);                                    \
        __builtin_amdgcn_s_setprio(1);                                           \
        _Pragma("unroll")                                                        \
        for (int nt = 0; nt < 8; ++nt) {                                         \
            int n = nt * 16 + lo;                                                \
            uint4 bz = *(const uint4*)(&zc_[n * 64 + ((hi ^ (n & 7)) << 3)]);    \
            _Pragma("unroll")                                                    \
            for (int mi = 0; mi < 4; ++mi)                                       \
                acc[mi][nt] = mfma16(aP[mi], bz, acc[mi][nt]);                   \
        }                                                                        \
        __builtin_amdgcn_s_setprio(0);                                           \
        if ((L) + 1 < L_LAYERS) {                                                \
            _Pragma("unroll")                                                    \
            for (int mi = 0; mi < 4; ++mi)                                       \
                aP[mi] = swv[((((L) + 1) * 16 + w * 4 + mi) * 2 + 0) * 64 + l];  \
        }                                                                        \
        __builtin_amdgcn_s_setprio(1);                                           \
        _Pragma("unroll")                                                        \
        for (int nt = 0; nt < 8; ++nt) {                                         \
            int n = nt * 16 + lo;                                                \
            uint4 bz = *(const uint4*)(&zc_[n * 64 + (((4 + hi) ^ (n & 7)) << 3)]);\
            _Pragma("unroll")                                                    \
            for (int mi = 0; mi < 4; ++mi)                                       \
                acc[mi][nt] = mfma16(a1_[mi], bz, acc[mi][nt]);                  \
        }                                                                        \
        __builtin_amdgcn_s_setprio(0);                                           \
        bar_lgkm();                                                              \
    }

__global__ __launch_bounds__(256) void skip_post(
    const u16* __restrict__ zT, const u16* __restrict__ swpAll,
    const float* __restrict__ sbsum,
    const u16* __restrict__ pp1p, const float* __restrict__ pp1b,
    const u16* __restrict__ pp2p, const float* __restrict__ pp2b,
    float* __restrict__ out)
{
    __shared__ u16 lds[128 * 256];    // 64 KB; phase1: two 16KB z bufs; phase2: sl 128x256
    int tid = threadIdx.x;
    int w = tid >> 6, l = tid & 63;
    int lo = l & 15, hi = l >> 4;
    int wg = xcd_swz512(blockIdx.x);
    int b = wg >> 7, t0 = (wg & 127) * 128;

    // staging identity: 4 chunks (16B) per thread (128 rows x 8 granules)
    size_t goff[4];
    int loff[4];
#pragma unroll
    for (int j = 0; j < 4; ++j) {
        int idx = tid + j * 256;
        int row = idx >> 3, s = idx & 7;
        goff[j] = ((size_t)t0 + row) * 64 + s * 8;
        loff[j] = row * 64 + ((s ^ (row & 7)) << 3);
    }

    f32x4 acc[4][8];
#pragma unroll
    for (int mi = 0; mi < 4; ++mi) {
        f32x4 iS;
#pragma unroll
        for (int r = 0; r < 4; ++r) iS[r] = sbsum[(w * 4 + mi) * 16 + hi * 4 + r];
#pragma unroll
        for (int nt = 0; nt < 8; ++nt) acc[mi][nt] = iS;
    }

    const uint4* swv = (const uint4*)swpAll;
    // prologue: L0 -> buf0; L1 -> rA; L2 -> rB; layer-0 kk0 weights -> aP
    {
        const u16* z0 = zT + (size_t)b * T_LEN * 64;
#pragma unroll
        for (int j = 0; j < 4; ++j)
            *(uint4*)(&lds[loff[j]]) = *(const uint4*)(z0 + goff[j]);
    }
    uint4 rA[4], rB[4];
    {
        const u16* z1 = zT + ((size_t)(1 * 4 + b)) * T_LEN * 64;
        const u16* z2 = zT + ((size_t)(2 * 4 + b)) * T_LEN * 64;
#pragma unroll
        for (int j = 0; j < 4; ++j) {
            rA[j] = *(const uint4*)(z1 + goff[j]);
            rB[j] = *(const uint4*)(z2 + goff[j]);
        }
    }
    uint4 aP[4];
#pragma unroll
    for (int mi = 0; mi < 4; ++mi)
        aP[mi] = swv[((w * 4 + mi) * 2 + 0) * 64 + l];
    bar_lgkm();

    for (int i = 0; i < L_LAYERS; i += 2) {
        SPX(i,     0, 1, rA);       // layer i   (even) from buf0
        SPX(i + 1, 1, 0, rB);       // layer i+1 (odd)  from buf1
    }

    // ---- relu(skip) -> sl (bf16, swizzled; 128 rows x 256 cols) ----
#pragma unroll
    for (int mi = 0; mi < 4; ++mi) {
#pragma unroll
        for (int nt = 0; nt < 8; ++nt) {
            int n = nt * 16 + lo;
            int k0 = (w * 4 + mi) * 16 + hi * 4;
            int col = k0 ^ ((n & 15) << 3);
            float v0 = acc[mi][nt][0], v1 = acc[mi][nt][1], v2 = acc[mi][nt][2], v3 = acc[mi][nt][3];
            v0 = v0 > 0.f ? v0 : 0.f; v1 = v1 > 0.f ? v1 : 0.f;
            v2 = v2 > 0.f ? v2 : 0.f; v3 = v3 > 0.f ? v3 : 0.f;
            *(unsigned*)(&lds[n * 256 + col]) = cvt2(v0, v1);
            *(unsigned*)(&lds[n * 256 + col + 2]) = cvt2(v2, v3);
        }
    }
    __syncthreads();

    // ---- pp1 ----
    f32x4 u[4][8];
#pragma unroll
    for (int mi = 0; mi < 4; ++mi) {
        f32x4 iU;
#pragma unroll
        for (int r = 0; r < 4; ++r) iU[r] = pp1b[(w * 4 + mi) * 16 + hi * 4 + r];
#pragma unroll
        for (int nt = 0; nt < 8; ++nt) u[mi][nt] = iU;
    }
    {
        const uint4* p1v = (const uint4*)pp1p;
#pragma unroll
        for (int kk = 0; kk < 8; ++kk) {
            uint4 a[4];
#pragma unroll
            for (int mi = 0; mi < 4; ++mi)
                a[mi] = p1v[((w * 4 + mi) * 8 + kk) * 64 + l];
#pragma unroll
            for (int nt = 0; nt < 8; ++nt) {
                int n = nt * 16 + lo;
                int kb = kk * 32 + hi * 8;
                uint4 bz = *(const uint4*)(&lds[n * 256 + (kb ^ ((n & 15) << 3))]);
#pragma unroll
                for (int mi = 0; mi < 4; ++mi)
                    u[mi][nt] = mfma16(a[mi], bz, u[mi][nt]);
            }
        }
    }
    __syncthreads();
#pragma unroll
    for (int mi = 0; mi < 4; ++mi) {
#pragma unroll
        for (int nt = 0; nt < 8; ++nt) {
            int n = nt * 16 + lo;
            int k0 = (w * 4 + mi) * 16 + hi * 4;
            int col = k0 ^ ((n & 15) << 3);
            float v0 = u[mi][nt][0], v1 = u[mi][nt][1], v2 = u[mi][nt][2], v3 = u[mi][nt][3];
            v0 = v0 > 0.f ? v0 : 0.f; v1 = v1 > 0.f ? v1 : 0.f;
            v2 = v2 > 0.f ? v2 : 0.f; v3 = v3 > 0.f ? v3 : 0.f;
            *(unsigned*)(&lds[n * 256 + col]) = cvt2(v0, v1);
            *(unsigned*)(&lds[n * 256 + col + 2]) = cvt2(v2, v3);
        }
    }
    __syncthreads();

    // ---- pp2 ----
    f32x4 vv[4][8];
#pragma unroll
    for (int mi = 0; mi < 4; ++mi) {
        f32x4 iV;
#pragma unroll
        for (int r = 0; r < 4; ++r) iV[r] = pp2b[(w * 4 + mi) * 16 + hi * 4 + r];
#pragma unroll
        for (int nt = 0; nt < 8; ++nt) vv[mi][nt] = iV;
    }
    {
        const uint4* p2v = (const uint4*)pp2p;
#pragma unroll
        for (int kk = 0; kk < 8; ++kk) {
            uint4 a[4];
#pragma unroll
            for (int mi = 0; mi < 4; ++mi)
                a[mi] = p2v[((w * 4 + mi) * 8 + kk) * 64 + l];
#pragma unroll
            for (int nt = 0; nt < 8; ++nt) {
                int n = nt * 16 + lo;
                int kb = kk * 32 + hi * 8;
                uint4 bz = *(const uint4*)(&lds[n * 256 + (kb ^ ((n & 15) << 3))]);
#pragma unroll
                for (int mi = 0; mi < 4; ++mi)
                    vv[mi][nt] = mfma16(a[mi], bz, vv[mi][nt]);
            }
        }
    }
#pragma unroll
    for (int mi = 0; mi < 4; ++mi) {
#pragma unroll
        for (int nt = 0; nt < 8; ++nt) {
            int t = t0 + nt * 16 + lo;
            int p0 = (w * 4 + mi) * 16 + hi * 4;
#pragma unroll
            for (int r = 0; r < 4; ++r)
                out[((size_t)b * 256 + p0 + r) * T_LEN + t] = vv[mi][nt][r];
        }
    }
}

// ================= plan C post (fp32 skipsum fallback) =================
__global__ __launch_bounds__(256) void post_mfma(
    const float* __restrict__ skipsum,
    const u16* __restrict__ pp1p, const float* __restrict__ pp1b,
    const u16* __restrict__ pp2p, const float* __restrict__ pp2b,
    float* __restrict__ out)
{
    __shared__ u16 sl[64 * 256];
    int tid = threadIdx.x;
    int w = tid >> 6, l = tid & 63;
    int lo = l & 15, hi = l >> 4;
    int nblk = T_LEN / 64;
    int b = blockIdx.x / nblk, t0 = (blockIdx.x % nblk) * 64;

#pragma unroll
    for (int mi = 0; mi < 4; ++mi) {
#pragma unroll
        for (int nt = 0; nt < 4; ++nt) {
            int n = nt * 16 + lo;
            int t = t0 + n;
            int p0 = (w * 4 + mi) * 16 + hi * 4;
            float v[4];
#pragma unroll
            for (int r = 0; r < 4; ++r) {
                float s = skipsum[((size_t)b * 256 + p0 + r) * T_LEN + t];
                v[r] = s > 0.f ? s : 0.f;
            }
            int col = p0 ^ ((n & 15) << 3);
            *(unsigned*)(&sl[n * 256 + col]) = cvt2(v[0], v[1]);
            *(unsigned*)(&sl[n * 256 + col + 2]) = cvt2(v[2], v[3]);
        }
    }
    __syncthreads();

    f32x4 u[4][4];
#pragma unroll
    for (int mi = 0; mi < 4; ++mi) {
        f32x4 iU;
#pragma unroll
        for (int r = 0; r < 4; ++r) iU[r] = pp1b[(w * 4 + mi) * 16 + hi * 4 + r];
#pragma unroll
        for (int nt = 0; nt < 4; ++nt) u[mi][nt] = iU;
    }
    {
        const uint4* p1v = (const uint4*)pp1p;
#pragma unroll
        for (int kk = 0; kk < 8; ++kk) {
            uint4 a[4];
#pragma unroll
            for (int mi = 0; mi < 4; ++mi)
                a[mi] = p1v[((w * 4 + mi) * 8 + kk) * 64 + l];
#pragma unroll
            for (int nt = 0; nt < 4; ++nt) {
                int n = nt * 16 + lo;
                int kb = kk * 32 + hi * 8;
                uint4 bz = *(const uint4*)(&sl[n * 256 + (kb ^ ((n & 15) << 3))]);
#pragma unroll
                for (int mi = 0; mi < 4; ++mi)
                    u[mi][nt] = mfma16(a[mi], bz, u[mi][nt]);
            }
        }
    }
    __syncthreads();
#pragma unroll
    for (int mi = 0; mi < 4; ++mi) {
#pragma unroll
        for (int nt = 0; nt < 4; ++nt) {
            int n = nt * 16 + lo;
            int k0 = (w * 4 + mi) * 16 + hi * 4;
            int col = k0 ^ ((n & 15) << 3);
            float v0 = u[mi][nt][0], v1 = u[mi][nt][1], v2 = u[mi][nt][2], v3 = u[mi][nt][3];
            v0 = v0 > 0.f ? v0 : 0.f; v1 = v1 > 0.f ? v1 : 0.f;
            v2 = v2 > 0.f ? v2 : 0.f; v3 = v3 > 0.f ? v3 : 0.f;
            *(unsigned*)(&sl[n * 256 + col]) = cvt2(v0, v1);
            *(unsigned*)(&sl[n * 256 + col + 2]) = cvt2(v2, v3);
        }
    }
    __syncthreads();

    f32x4 vv[4][4];
#pragma unroll
    for (int mi = 0; mi < 4; ++mi) {
        f32x4 iV;
#pragma unroll
        for (int r = 0; r < 4; ++r) iV[r] = pp2b[(w * 4 + mi) * 16 + hi * 4 + r];
#pragma unroll
        for (int nt = 0; nt < 4; ++nt) vv[mi][nt] = iV;
    }
    {
        const uint4* p2v = (const uint4*)pp2p;
#pragma unroll
        for (int kk = 0; kk < 8; ++kk) {
            uint4 a[4];
#pragma unroll
            for (int mi = 0; mi < 4; ++mi)
                a[mi] = p2v[((w * 4 + mi) * 8 + kk) * 64 + l];
#pragma unroll
            for (int nt = 0; nt < 4; ++nt) {
                int n = nt * 16 + lo;
                int kb = kk * 32 + hi * 8;
                uint4 bz = *(const uint4*)(&sl[n * 256 + (kb ^ ((n & 15) << 3))]);
#pragma unroll
                for (int mi = 0; mi < 4; ++mi)
                    vv[mi][nt] = mfma16(a[mi], bz, vv[mi][nt]);
            }
        }
    }
#pragma unroll
    for (int mi = 0; mi < 4; ++mi) {
#pragma unroll
        for (int nt = 0; nt < 4; ++nt) {
            int t = t0 + nt * 16 + lo;
            int p0 = (w * 4 + mi) * 16 + hi * 4;
#pragma unroll
            for (int r = 0; r < 4; ++r)
                out[((size_t)b * 256 + p0 + r) * T_LEN + t] = vv[mi][nt][r];
        }
    }
}

// ================= launch =================
extern "C" void kernel_launch(void* const* d_in, const int* in_sizes, int n_in,
                              void* d_out, int out_size, void* d_ws, size_t ws_size,
                              hipStream_t stream)
{
    const float* x      = (const float*)d_in[0];
    const float* pre_w  = (const float*)d_in[1];
    const float* pre_b  = (const float*)d_in[2];
    const float* filt_w = (const float*)d_in[3];
    const float* filt_b = (const float*)d_in[4];
    const float* gate_w = (const float*)d_in[5];
    const float* gate_b = (const float*)d_in[6];
    const float* res_w  = (const float*)d_in[7];
    const float* res_b  = (const float*)d_in[8];
    const float* skip_w = (const float*)d_in[9];
    const float* skip_b = (const float*)d_in[10];
    const float* pp1_w  = (const float*)d_in[11];
    const float* pp1_b  = (const float*)d_in[12];
    const float* pp2_w  = (const float*)d_in[13];
    const float* pp2_b  = (const float*)d_in[14];
    float* outp = (float*)d_out;

    // bf16 h ping-pong in d_out (2 x 8.4 MB; final out overwrites all of d_out)
    u16* ht0 = (u16*)outp;
    u16* ht1 = ht0 + (size_t)B_SZ * T_LEN * 64;

    const size_t ZT_BYTES   = (size_t)L_LAYERS * B_SZ * T_LEN * 64 * 2;   // 167,772,160
    const size_t SKIP_BYTES = (size_t)B_SZ * SKIP_C * T_LEN * 4;          // 67,108,864

    const bool useZ = ws_size >= ZT_BYTES + (size_t)2 * 1024 * 1024;

    char* ws = (char*)d_ws;
    u16*   zT      = (u16*)ws;
    float* skipsum = (float*)ws;
    size_t packoff = useZ ? ZT_BYTES : SKIP_BYTES;
    u16* w1p  = (u16*)(ws + packoff);
    u16* swp  = w1p + 327680;
    u16* rwp  = swp + 327680;
    u16* pp1p = rwp + 81920;
    u16* pp2p = pp1p + 65536;
    u16* prep = pp2p + 65536;
    float* sbsum = (float*)(prep + 16384);

    repack2<<<3457, 256, 0, stream>>>(filt_w, gate_w, skip_w, res_w, pp1_w, pp2_w, pre_w, skip_b,
                                      w1p, swp, rwp, pp1p, pp2p, prep, sbsum);

    pre_mfma<<<1024, 256, 0, stream>>>(x, prep, pre_b, ht0);

    const u16* hi_ = ht0; u16* ho_ = ht1;
    for (int i = 0; i < L_LAYERS; ++i) {
        int d = 1 << (i % 10);
        int first = (i == 0) ? 1 : 0;
        int last  = (i == L_LAYERS - 1) ? 1 : 0;
        if (useZ)
            layer_mfma<0><<<1024, 256, 0, stream>>>(
                hi_, ho_,
                zT + (size_t)i * 4194304, skipsum,
                w1p + (size_t)i * 16384, swp + (size_t)i * 16384, rwp + (size_t)i * 4096,
                filt_b + i * 64, gate_b + i * 64, skip_b + i * 256, res_b + i * 64,
                d, first, last);
        else
            layer_mfma<1><<<1024, 256, 0, stream>>>(
                hi_, ho_,
                zT, skipsum,
                w1p + (size_t)i * 16384, swp + (size_t)i * 16384, rwp + (size_t)i * 4096,
                filt_b + i * 64, gate_b + i * 64, skip_b + i * 256, res_b + i * 64,
                d, first, last);
        { const u16* tf = hi_; hi_ = ho_; ho_ = (u16*)tf; }
    }

    if (useZ)
        skip_post<<<512, 256, 0, stream>>>(zT, swp, sbsum, pp1p, pp1_b, pp2p, pp2_b, outp);
    else
        post_mfma<<<1024, 256, 0, stream>>>(skipsum, pp1p, pp1_b, pp2p, pp2_b, outp);
}

// Round 14
// 278.904 us; speedup vs baseline: 1.2043x; 1.2043x over previous
//
#include <hip/hip_runtime.h>

#define T_LEN   16384
#define B_SZ    4
#define AUDIO_C 256
#define RES_C   64
#define SKIP_C  256
#define L_LAYERS 20

typedef unsigned short u16;
using bf16x8 = __attribute__((ext_vector_type(8))) __bf16;
using f32x4  = __attribute__((ext_vector_type(4))) float;

__device__ __forceinline__ u16 f2bf(float x){
    union { float f; unsigned u; } v; v.f = x;
    return (u16)((v.u + 0x7FFFu + ((v.u >> 16) & 1u)) >> 16);
}
// compiler-fused v_cvt_pk_bf16_f32 (a -> low 16, b -> high 16)
__device__ __forceinline__ unsigned cvt2(float a, float b){
    union { __bf16 h[2]; unsigned u; } r;
    r.h[0] = (__bf16)a; r.h[1] = (__bf16)b;
    return r.u;
}
__device__ __forceinline__ float bflo(unsigned u){ union{unsigned q; float f;} v; v.q = u << 16; return v.f; }
__device__ __forceinline__ float bfhi(unsigned u){ union{unsigned q; float f;} v; v.q = u & 0xffff0000u; return v.f; }
__device__ __forceinline__ f32x4 mfma16(uint4 a, uint4 b, f32x4 c){
    return __builtin_amdgcn_mfma_f32_16x16x32_bf16(
        __builtin_bit_cast(bf16x8, a), __builtin_bit_cast(bf16x8, b), c, 0, 0, 0);
}
// XCD-aware bijective swizzle for grid=1024 (8 XCDs x 128 chunk)
__device__ __forceinline__ int xcd_swz1k(int bid){ return (bid & 7) * 128 + (bid >> 3); }
// raw barrier: LDS visibility only — VMEM loads stay in flight (no vmcnt(0) drain)
__device__ __forceinline__ void bar_lgkm(){
    asm volatile("s_waitcnt lgkmcnt(0)" ::: "memory");
    __builtin_amdgcn_s_barrier();
    asm volatile("" ::: "memory");
}

// ================= repack: weights -> per-lane MFMA A-fragments (bf16) =================
__global__ __launch_bounds__(256) void repack2(
    const float* __restrict__ fw, const float* __restrict__ gw,
    const float* __restrict__ sw, const float* __restrict__ rw,
    const float* __restrict__ p1, const float* __restrict__ p2,
    const float* __restrict__ prw, const float* __restrict__ sb,
    u16* __restrict__ w1p, u16* __restrict__ swp, u16* __restrict__ rwp,
    u16* __restrict__ pp1p, u16* __restrict__ pp2p,
    u16* __restrict__ prep, float* __restrict__ sbsum)
{
    int idx = blockIdx.x * 256 + threadIdx.x;
    if (idx < 327680) {                             // w1p: GEMM1 A, K=128
        int j = idx & 7, l = (idx >> 3) & 63, kk = (idx >> 9) & 3, mt = (idx >> 11) & 7, i = idx >> 14;
        int m = mt * 16 + (l & 15);
        int k = kk * 32 + (l >> 4) * 8 + j;
        const float* srcw = (m < 64) ? fw : gw;
        int mm = m & 63, c = k & 63, tap = k >> 6;
        w1p[idx] = f2bf(srcw[((i * 64 + mm) * 64 + c) * 2 + tap]);
        return;
    }
    idx -= 327680;
    if (idx < 327680) {                             // swp: skip A, K=64
        int j = idx & 7, l = (idx >> 3) & 63, kk = (idx >> 9) & 1, mt = (idx >> 10) & 15, i = idx >> 14;
        int p = mt * 16 + (l & 15);
        int c = kk * 32 + (l >> 4) * 8 + j;
        swp[idx] = f2bf(sw[(i * 256 + p) * 64 + c]);
        return;
    }
    idx -= 327680;
    if (idx < 81920) {                              // rwp: res A, K=64
        int j = idx & 7, l = (idx >> 3) & 63, kk = (idx >> 9) & 1, mt = (idx >> 10) & 3, i = idx >> 12;
        int o = mt * 16 + (l & 15);
        int c = kk * 32 + (l >> 4) * 8 + j;
        rwp[idx] = f2bf(rw[(i * 64 + o) * 64 + c]);
        return;
    }
    idx -= 81920;
    if (idx < 65536) {                              // pp1p: K=256
        int j = idx & 7, l = (idx >> 3) & 63, kk = (idx >> 9) & 7, mt = idx >> 12;
        int m = mt * 16 + (l & 15);
        int k = kk * 32 + (l >> 4) * 8 + j;
        pp1p[idx] = f2bf(p1[m * 256 + k]);
        return;
    }
    idx -= 65536;
    if (idx < 65536) {                              // pp2p: K=256
        int j = idx & 7, l = (idx >> 3) & 63, kk = (idx >> 9) & 7, mt = idx >> 12;
        int m = mt * 16 + (l & 15);
        int k = kk * 32 + (l >> 4) * 8 + j;
        pp2p[idx] = f2bf(p2[m * 256 + k]);
        return;
    }
    idx -= 65536;
    if (idx < 16384) {                              // prep: pre A, M=64, K=256
        int j = idx & 7, l = (idx >> 3) & 63, kk = (idx >> 9) & 7, mt = idx >> 12;
        int m = mt * 16 + (l & 15);
        int k = kk * 32 + (l >> 4) * 8 + j;
        prep[idx] = f2bf(prw[m * 256 + k]);
        return;
    }
    idx -= 16384;
    if (idx < 256) {                                // sbsum[p] = sum_i skip_b[i][p]
        float s = 0.f;
        for (int i = 0; i < L_LAYERS; ++i) s += sb[i * 256 + idx];
        sbsum[idx] = s;
        return;
    }
}

// ================= pre (MFMA): ht[b][t][o] (bf16) = pre_w @ x + pre_b ==================
__global__ __launch_bounds__(256) void pre_mfma(
    const float* __restrict__ x, const u16* __restrict__ prep,
    const float* __restrict__ pre_b, u16* __restrict__ ht)
{
    __shared__ u16 sx[64 * 256];                    // 32 KB
    unsigned* sx32 = (unsigned*)sx;
    int tid = threadIdx.x;
    int w = tid >> 6, l = tid & 63;
    int lo = l & 15, hi = l >> 4;
    int wg = xcd_swz1k(blockIdx.x);
    int b = wg >> 8, t0 = (wg & 255) * 64;

    // weight fragments issued first (stay in flight across the raw barrier)
    const uint4* av = (const uint4*)prep;
    uint4 a[8];
#pragma unroll
    for (int kk = 0; kk < 8; ++kk) a[kk] = av[(w * 8 + kk) * 64 + l];

    {
        int t = l;
        const float* xb = x + (size_t)b * AUDIO_C * T_LEN + t0 + t;
#pragma unroll 8
        for (int c2 = 0; c2 < 64; c2 += 2) {
            int c = w * 64 + c2;
            float v0 = xb[(size_t)c * T_LEN];
            float v1 = xb[(size_t)(c + 1) * T_LEN];
            int ch = c >> 3;
            int a32 = t * 128 + ((ch ^ (t & 7)) << 2) + ((c >> 1) & 3);
            sx32[a32] = cvt2(v0, v1);
        }
    }
    bar_lgkm();

    f32x4 acc[4];
    {
        f32x4 ib;
#pragma unroll
        for (int r = 0; r < 4; ++r) ib[r] = pre_b[w * 16 + hi * 4 + r];
#pragma unroll
        for (int nt = 0; nt < 4; ++nt) acc[nt] = ib;
    }
#pragma unroll
    for (int kk = 0; kk < 8; ++kk) {
#pragma unroll
        for (int nt = 0; nt < 4; ++nt) {
            int t = nt * 16 + lo;
            int ch = kk * 4 + hi;
            uint4 bv = *(const uint4*)&sx32[t * 128 + ((ch ^ (t & 7)) << 2)];
            acc[nt] = mfma16(a[kk], bv, acc[nt]);
        }
    }
#pragma unroll
    for (int nt = 0; nt < 4; ++nt) {
        int t = t0 + nt * 16 + lo;
        uint2 ov;
        ov.x = cvt2(acc[nt][0], acc[nt][1]);
        ov.y = cvt2(acc[nt][2], acc[nt][3]);
        *(uint2*)(ht + ((size_t)b * T_LEN + t) * 64 + w * 16 + hi * 4) = ov;
    }
}

// ========== fused gated layer (t64/grid1024; h bf16 t-major; epilogue h from LDS) =========
template<int DO_SKIP>
__global__ __launch_bounds__(256) void layer_mfma(
    const u16* __restrict__ htin, u16* __restrict__ htout,
    u16* __restrict__ zTi, float* __restrict__ skipsum,
    const u16* __restrict__ w1p, const u16* __restrict__ swp, const u16* __restrict__ rwp,
    const float* __restrict__ fb, const float* __restrict__ gb,
    const float* __restrict__ sb, const float* __restrict__ rb,
    int d, int first, int last)
{
    __shared__ u16 hl[2 * 64 * 64];   // region0 = tap t-d, region1 = tap t (bf16)
    __shared__ u16 zl[64 * 64];       // 8 KB
    int tid = threadIdx.x;
    int w = tid >> 6, l = tid & 63;
    int lo = l & 15, hi = l >> 4;
    int wg = xcd_swz1k(blockIdx.x);
    int b = wg >> 8, t0 = (wg & 255) * 64;
    const u16* hb = htin + (size_t)b * T_LEN * 64;

    // ---- stage both taps (pure bf16 copy, no conversion): 1024 chunks, 4/thread ----
#pragma unroll
    for (int k = 0; k < 4; ++k) {
        int id = tid + k * 256;
        int region = id >> 9;             // 0 = tap t-d, 1 = tap t
        int row = (id >> 3) & 63;
        int g = id & 7;                   // 16B granule (8 channels)
        int t = region ? (t0 + row) : (t0 - d + row);
        uint4 bv = make_uint4(0u, 0u, 0u, 0u);
        if (t >= 0) bv = *(const uint4*)(hb + (size_t)t * 64 + g * 8);
        *(uint4*)(&hl[(region << 12) + row * 64 + ((g ^ (row & 7)) << 3)]) = bv;
    }

    // ---- weight fragments (L2) issued while stage is in flight ----
    const uint4* w1v = (const uint4*)w1p;
    uint4 aF[4], aG[4];
#pragma unroll
    for (int kk = 0; kk < 4; ++kk) {
        aF[kk] = w1v[(w * 4 + kk) * 64 + l];
        aG[kk] = w1v[((w + 4) * 4 + kk) * 64 + l];
    }
    uint4 aR[2];
    if (!last) {
        const uint4* rwv = (const uint4*)rwp;
        aR[0] = rwv[(w * 2 + 0) * 64 + l];
        aR[1] = rwv[(w * 2 + 1) * 64 + l];
    }
    f32x4 accF[4], accG[4];
    {
        f32x4 iF, iG;
#pragma unroll
        for (int r = 0; r < 4; ++r) { iF[r] = fb[w * 16 + hi * 4 + r]; iG[r] = gb[w * 16 + hi * 4 + r]; }
#pragma unroll
        for (int nt = 0; nt < 4; ++nt) { accF[nt] = iF; accG[nt] = iG; }
    }
    bar_lgkm();               // weight/VMEM loads NOT drained

    // ---- phase 1: GEMM1 from LDS (kk0,1 -> tap t-d; kk2,3 -> tap t) ----
    __builtin_amdgcn_s_setprio(1);
#pragma unroll
    for (int nt = 0; nt < 4; ++nt) {
        int n = nt * 16 + lo;
#pragma unroll
        for (int kk = 0; kk < 4; ++kk) {
            int gq = (kk & 1) * 4 + hi;
            uint4 bv = *(const uint4*)(&hl[(kk >> 1) * 4096 + n * 64 + ((gq ^ (n & 7)) << 3)]);
            accF[nt] = mfma16(aF[kk], bv, accF[nt]);
            accG[nt] = mfma16(aG[kk], bv, accG[nt]);
        }
    }
    __builtin_amdgcn_s_setprio(0);

    // ---- activation + z staging (LDS only) ----
#pragma unroll
    for (int nt = 0; nt < 4; ++nt) {
        float zv[4];
#pragma unroll
        for (int r = 0; r < 4; ++r) {
            float f = accF[nt][r], g = accG[nt][r];
            float ef = __expf(2.f * f);
            float th = 1.f - 2.f * __builtin_amdgcn_rcpf(ef + 1.f);
            float sg = __builtin_amdgcn_rcpf(1.f + __expf(-g));
            zv[r] = th * sg;
        }
        int n = nt * 16 + lo;
        int k0 = w * 16 + hi * 4;
        int col = k0 ^ ((n & 7) << 3);
        *(unsigned*)(&zl[n * 64 + col]) = cvt2(zv[0], zv[1]);
        *(unsigned*)(&zl[n * 64 + col + 2]) = cvt2(zv[2], zv[3]);
    }
    bar_lgkm();

    // ---- bulk coalesced z write: fire-and-forget under phase-2 MFMAs ----
    if (!DO_SKIP) {
#pragma unroll
        for (int q = 0; q < 2; ++q) {
            int idx = tid + q * 256;          // 512 chunks of 16B
            int row = idx >> 3, s = idx & 7;
            uint4 v = *(const uint4*)(&zl[row * 64 + ((s ^ (row & 7)) << 3)]);
            *(uint4*)(zTi + ((size_t)b * T_LEN + t0 + row) * 64 + s * 8) = v;
        }
    }

    // ---- phase 2: res GEMM (+ skip GEMM for plan C) ----
    uint4 aS[4][2];
    f32x4 accS[4][4];
    if (DO_SKIP) {
        const uint4* swv = (const uint4*)swp;
#pragma unroll
        for (int mi = 0; mi < 4; ++mi) {
            aS[mi][0] = swv[((w * 4 + mi) * 2 + 0) * 64 + l];
            aS[mi][1] = swv[((w * 4 + mi) * 2 + 1) * 64 + l];
            f32x4 iS;
#pragma unroll
            for (int r = 0; r < 4; ++r) iS[r] = sb[(w * 4 + mi) * 16 + hi * 4 + r];
#pragma unroll
            for (int nt = 0; nt < 4; ++nt) accS[mi][nt] = iS;
        }
    }
    f32x4 accR[4];
    if (!last) {
        f32x4 iR;
#pragma unroll
        for (int r = 0; r < 4; ++r) iR[r] = rb[w * 16 + hi * 4 + r];
#pragma unroll
        for (int nt = 0; nt < 4; ++nt) accR[nt] = iR;
    }
    __builtin_amdgcn_s_setprio(1);
#pragma unroll
    for (int nt = 0; nt < 4; ++nt) {
        int n = nt * 16 + lo;
#pragma unroll
        for (int kk = 0; kk < 2; ++kk) {
            int kb = kk * 32 + hi * 8;
            uint4 bz = *(const uint4*)(&zl[n * 64 + (kb ^ ((n & 7) << 3))]);
            if (!last) accR[nt] = mfma16(aR[kk], bz, accR[nt]);
            if (DO_SKIP) {
#pragma unroll
                for (int mi = 0; mi < 4; ++mi)
                    accS[mi][nt] = mfma16(aS[mi][kk], bz, accS[mi][nt]);
            }
        }
    }
    __builtin_amdgcn_s_setprio(0);

    // ---- epilogue: h_out = h_in(bf16, from LDS region 1) + res ----
    if (!last) {
        int ch = w * 2 + (hi >> 1);
        int halfo = (hi & 1) * 4;             // u16 offset within 16B chunk
#pragma unroll
        for (int nt = 0; nt < 4; ++nt) {
            int n = nt * 16 + lo;
            uint2 hp = *(const uint2*)(&hl[4096 + n * 64 + ((ch ^ (n & 7)) << 3) + halfo]);
            float o0 = bflo(hp.x) + accR[nt][0];
            float o1 = bfhi(hp.x) + accR[nt][1];
            float o2 = bflo(hp.y) + accR[nt][2];
            float o3 = bfhi(hp.y) + accR[nt][3];
            uint2 ov;
            ov.x = cvt2(o0, o1);
            ov.y = cvt2(o2, o3);
            int t = t0 + n;
            *(uint2*)(htout + ((size_t)b * T_LEN + t) * 64 + w * 16 + hi * 4) = ov;
        }
    }
    if (DO_SKIP) {
#pragma unroll
        for (int mi = 0; mi < 4; ++mi) {
#pragma unroll
            for (int nt = 0; nt < 4; ++nt) {
                int t = t0 + nt * 16 + lo;
                int p0 = (w * 4 + mi) * 16 + hi * 4;
#pragma unroll
                for (int r = 0; r < 4; ++r) {
                    float* sp = &skipsum[((size_t)b * 256 + p0 + r) * T_LEN + t];
                    float v = accS[mi][nt][r];
                    if (first) *sp = v; else *sp = *sp + v;
                }
            }
        }
    }
}

// ==== fused skip-reduce + pp1 + pp2 (t64/grid1024; 2 LAYERS PER BODY, 10 barriers) ====
// lds: 4 z-buffers of 8 KB (buf j at j*4096 u16); reused as sl[64][256] for pp phase.
#define SPL(L, BUF)                                                              \
    {                                                                            \
        uint4 a1_[4];                                                            \
        _Pragma("unroll")                                                        \
        for (int mi = 0; mi < 4; ++mi)                                           \
            a1_[mi] = swv[(((L) * 16 + w * 4 + mi) * 2 + 1) * 64 + l];           \
        const u16* zc_ = lds + ((BUF) << 12);                                    \
        __builtin_amdgcn_s_setprio(1);                                           \
        _Pragma("unroll")                                                        \
        for (int nt = 0; nt < 4; ++nt) {                                         \
            int n = nt * 16 + lo;                                                \
            uint4 bz = *(const uint4*)(&zc_[n * 64 + ((hi ^ (n & 7)) << 3)]);    \
            _Pragma("unroll")                                                    \
            for (int mi = 0; mi < 4; ++mi)                                       \
                acc[mi][nt] = mfma16(aP[mi], bz, acc[mi][nt]);                   \
        }                                                                        \
        __builtin_amdgcn_s_setprio(0);                                           \
        if ((L) + 1 < L_LAYERS) {                                                \
            _Pragma("unroll")                                                    \
            for (int mi = 0; mi < 4; ++mi)                                       \
                aP[mi] = swv[((((L) + 1) * 16 + w * 4 + mi) * 2 + 0) * 64 + l];  \
        }                                                                        \
        __builtin_amdgcn_s_setprio(1);                                           \
        _Pragma("unroll")                                                        \
        for (int nt = 0; nt < 4; ++nt) {                                         \
            int n = nt * 16 + lo;                                                \
            uint4 bz = *(const uint4*)(&zc_[n * 64 + (((4 + hi) ^ (n & 7)) << 3)]);\
            _Pragma("unroll")                                                    \
            for (int mi = 0; mi < 4; ++mi)                                       \
                acc[mi][nt] = mfma16(a1_[mi], bz, acc[mi][nt]);                  \
        }                                                                        \
        __builtin_amdgcn_s_setprio(0);                                           \
    }

// body: process layers I, I+1 from bufs CUR*2, CUR*2+1; ds_write prefetched I+2,I+3
// into OTH bufs; issue loads for I+4, I+5. One barrier per body.
#define SP2(I, CUR, OTH)                                                         \
    {                                                                            \
        if ((I) + 2 < L_LAYERS) {                                                \
            u16* zn0_ = lds + (((OTH) * 2) << 12);                               \
            u16* zn1_ = lds + (((OTH) * 2 + 1) << 12);                           \
            *(uint4*)(&zn0_[loff0]) = rA0;                                       \
            *(uint4*)(&zn0_[loff1]) = rA1;                                       \
            *(uint4*)(&zn1_[loff0]) = rB0;                                       \
            *(uint4*)(&zn1_[loff1]) = rB1;                                       \
            if ((I) + 4 < L_LAYERS) {                                            \
                const u16* za_ = zT + ((size_t)(((I) + 4) * 4 + b)) * T_LEN * 64;\
                const u16* zb_ = zT + ((size_t)(((I) + 5) * 4 + b)) * T_LEN * 64;\
                rA0 = *(const uint4*)(za_ + goff0);                              \
                rA1 = *(const uint4*)(za_ + goff1);                              \
                rB0 = *(const uint4*)(zb_ + goff0);                              \
                rB1 = *(const uint4*)(zb_ + goff1);                              \
            }                                                                    \
        }                                                                        \
        SPL((I),     (CUR) * 2)                                                  \
        SPL((I) + 1, (CUR) * 2 + 1)                                              \
        bar_lgkm();                                                              \
    }

__global__ __launch_bounds__(256) void skip_post(
    const u16* __restrict__ zT, const u16* __restrict__ swpAll,
    const float* __restrict__ sbsum,
    const u16* __restrict__ pp1p, const float* __restrict__ pp1b,
    const u16* __restrict__ pp2p, const float* __restrict__ pp2b,
    float* __restrict__ out)
{
    __shared__ u16 lds[64 * 256];     // 32 KB; phase1: four 8KB z bufs; phase2: sl
    int tid = threadIdx.x;
    int w = tid >> 6, l = tid & 63;
    int lo = l & 15, hi = l >> 4;
    int wg = xcd_swz1k(blockIdx.x);
    int b = wg >> 8, t0 = (wg & 255) * 64;

    // staging identity: 2 chunks (16B) per lane per layer
    int idx0 = w * 128 + l, idx1 = idx0 + 64;
    int row0 = idx0 >> 3, s0 = idx0 & 7;
    int row1 = idx1 >> 3, s1 = idx1 & 7;
    size_t goff0 = ((size_t)t0 + row0) * 64 + s0 * 8;
    size_t goff1 = ((size_t)t0 + row1) * 64 + s1 * 8;
    int loff0 = row0 * 64 + ((s0 ^ (row0 & 7)) << 3);
    int loff1 = row1 * 64 + ((s1 ^ (row1 & 7)) << 3);

    f32x4 acc[4][4];
#pragma unroll
    for (int mi = 0; mi < 4; ++mi) {
        f32x4 iS;
#pragma unroll
        for (int r = 0; r < 4; ++r) iS[r] = sbsum[(w * 4 + mi) * 16 + hi * 4 + r];
#pragma unroll
        for (int nt = 0; nt < 4; ++nt) acc[mi][nt] = iS;
    }

    const uint4* swv = (const uint4*)swpAll;
    // prologue: layers 0,1 -> bufs 0,1; layers 2,3 -> rA/rB regs; layer-0 kk0 -> aP
    {
        const u16* z0 = zT + (size_t)b * T_LEN * 64;
        const u16* z1 = zT + ((size_t)(1 * 4 + b)) * T_LEN * 64;
        *(uint4*)(&lds[loff0]) = *(const uint4*)(z0 + goff0);
        *(uint4*)(&lds[loff1]) = *(const uint4*)(z0 + goff1);
        *(uint4*)(&lds[4096 + loff0]) = *(const uint4*)(z1 + goff0);
        *(uint4*)(&lds[4096 + loff1]) = *(const uint4*)(z1 + goff1);
    }
    const u16* z2 = zT + ((size_t)(2 * 4 + b)) * T_LEN * 64;
    const u16* z3 = zT + ((size_t)(3 * 4 + b)) * T_LEN * 64;
    uint4 rA0 = *(const uint4*)(z2 + goff0);
    uint4 rA1 = *(const uint4*)(z2 + goff1);
    uint4 rB0 = *(const uint4*)(z3 + goff0);
    uint4 rB1 = *(const uint4*)(z3 + goff1);
    uint4 aP[4];
#pragma unroll
    for (int mi = 0; mi < 4; ++mi)
        aP[mi] = swv[((w * 4 + mi) * 2 + 0) * 64 + l];
    bar_lgkm();

    SP2(0,  0, 1)
    SP2(2,  1, 0)
    SP2(4,  0, 1)
    SP2(6,  1, 0)
    SP2(8,  0, 1)
    SP2(10, 1, 0)
    SP2(12, 0, 1)
    SP2(14, 1, 0)
    SP2(16, 0, 1)
    SP2(18, 1, 0)

    // ---- relu(skip) -> sl (bf16, swizzled) ----
#pragma unroll
    for (int mi = 0; mi < 4; ++mi) {
#pragma unroll
        for (int nt = 0; nt < 4; ++nt) {
            int n = nt * 16 + lo;
            int k0 = (w * 4 + mi) * 16 + hi * 4;
            int col = k0 ^ ((n & 15) << 3);
            float v0 = acc[mi][nt][0], v1 = acc[mi][nt][1], v2 = acc[mi][nt][2], v3 = acc[mi][nt][3];
            v0 = v0 > 0.f ? v0 : 0.f; v1 = v1 > 0.f ? v1 : 0.f;
            v2 = v2 > 0.f ? v2 : 0.f; v3 = v3 > 0.f ? v3 : 0.f;
            *(unsigned*)(&lds[n * 256 + col]) = cvt2(v0, v1);
            *(unsigned*)(&lds[n * 256 + col + 2]) = cvt2(v2, v3);
        }
    }
    __syncthreads();

    // ---- pp1 ----
    f32x4 u[4][4];
#pragma unroll
    for (int mi = 0; mi < 4; ++mi) {
        f32x4 iU;
#pragma unroll
        for (int r = 0; r < 4; ++r) iU[r] = pp1b[(w * 4 + mi) * 16 + hi * 4 + r];
#pragma unroll
        for (int nt = 0; nt < 4; ++nt) u[mi][nt] = iU;
    }
    {
        const uint4* p1v = (const uint4*)pp1p;
#pragma unroll
        for (int kk = 0; kk < 8; ++kk) {
            uint4 a[4];
#pragma unroll
            for (int mi = 0; mi < 4; ++mi)
                a[mi] = p1v[((w * 4 + mi) * 8 + kk) * 64 + l];
#pragma unroll
            for (int nt = 0; nt < 4; ++nt) {
                int n = nt * 16 + lo;
                int kb = kk * 32 + hi * 8;
                uint4 bz = *(const uint4*)(&lds[n * 256 + (kb ^ ((n & 15) << 3))]);
#pragma unroll
                for (int mi = 0; mi < 4; ++mi)
                    u[mi][nt] = mfma16(a[mi], bz, u[mi][nt]);
            }
        }
    }
    __syncthreads();
#pragma unroll
    for (int mi = 0; mi < 4; ++mi) {
#pragma unroll
        for (int nt = 0; nt < 4; ++nt) {
            int n = nt * 16 + lo;
            int k0 = (w * 4 + mi) * 16 + hi * 4;
            int col = k0 ^ ((n & 15) << 3);
            float v0 = u[mi][nt][0], v1 = u[mi][nt][1], v2 = u[mi][nt][2], v3 = u[mi][nt][3];
            v0 = v0 > 0.f ? v0 : 0.f; v1 = v1 > 0.f ? v1 : 0.f;
            v2 = v2 > 0.f ? v2 : 0.f; v3 = v3 > 0.f ? v3 : 0.f;
            *(unsigned*)(&lds[n * 256 + col]) = cvt2(v0, v1);
            *(unsigned*)(&lds[n * 256 + col + 2]) = cvt2(v2, v3);
        }
    }
    __syncthreads();

    // ---- pp2 ----
    f32x4 vv[4][4];
#pragma unroll
    for (int mi = 0; mi < 4; ++mi) {
        f32x4 iV;
#pragma unroll
        for (int r = 0; r < 4; ++r) iV[r] = pp2b[(w * 4 + mi) * 16 + hi * 4 + r];
#pragma unroll
        for (int nt = 0; nt < 4; ++nt) vv[mi][nt] = iV;
    }
    {
        const uint4* p2v = (const uint4*)pp2p;
#pragma unroll
        for (int kk = 0; kk < 8; ++kk) {
            uint4 a[4];
#pragma unroll
            for (int mi = 0; mi < 4; ++mi)
                a[mi] = p2v[((w * 4 + mi) * 8 + kk) * 64 + l];
#pragma unroll
            for (int nt = 0; nt < 4; ++nt) {
                int n = nt * 16 + lo;
                int kb = kk * 32 + hi * 8;
                uint4 bz = *(const uint4*)(&lds[n * 256 + (kb ^ ((n & 15) << 3))]);
#pragma unroll
                for (int mi = 0; mi < 4; ++mi)
                    vv[mi][nt] = mfma16(a[mi], bz, vv[mi][nt]);
            }
        }
    }
#pragma unroll
    for (int mi = 0; mi < 4; ++mi) {
#pragma unroll
        for (int nt = 0; nt < 4; ++nt) {
            int t = t0 + nt * 16 + lo;
            int p0 = (w * 4 + mi) * 16 + hi * 4;
#pragma unroll
            for (int r = 0; r < 4; ++r)
                out[((size_t)b * 256 + p0 + r) * T_LEN + t] = vv[mi][nt][r];
        }
    }
}

// ================= plan C post (fp32 skipsum fallback) =================
__global__ __launch_bounds__(256) void post_mfma(
    const float* __restrict__ skipsum,
    const u16* __restrict__ pp1p, const float* __restrict__ pp1b,
    const u16* __restrict__ pp2p, const float* __restrict__ pp2b,
    float* __restrict__ out)
{
    __shared__ u16 sl[64 * 256];
    int tid = threadIdx.x;
    int w = tid >> 6, l = tid & 63;
    int lo = l & 15, hi = l >> 4;
    int nblk = T_LEN / 64;
    int b = blockIdx.x / nblk, t0 = (blockIdx.x % nblk) * 64;

#pragma unroll
    for (int mi = 0; mi < 4; ++mi) {
#pragma unroll
        for (int nt = 0; nt < 4; ++nt) {
            int n = nt * 16 + lo;
            int t = t0 + n;
            int p0 = (w * 4 + mi) * 16 + hi * 4;
            float v[4];
#pragma unroll
            for (int r = 0; r < 4; ++r) {
                float s = skipsum[((size_t)b * 256 + p0 + r) * T_LEN + t];
                v[r] = s > 0.f ? s : 0.f;
            }
            int col = p0 ^ ((n & 15) << 3);
            *(unsigned*)(&sl[n * 256 + col]) = cvt2(v[0], v[1]);
            *(unsigned*)(&sl[n * 256 + col + 2]) = cvt2(v[2], v[3]);
        }
    }
    __syncthreads();

    f32x4 u[4][4];
#pragma unroll
    for (int mi = 0; mi < 4; ++mi) {
        f32x4 iU;
#pragma unroll
        for (int r = 0; r < 4; ++r) iU[r] = pp1b[(w * 4 + mi) * 16 + hi * 4 + r];
#pragma unroll
        for (int nt = 0; nt < 4; ++nt) u[mi][nt] = iU;
    }
    {
        const uint4* p1v = (const uint4*)pp1p;
#pragma unroll
        for (int kk = 0; kk < 8; ++kk) {
            uint4 a[4];
#pragma unroll
            for (int mi = 0; mi < 4; ++mi)
                a[mi] = p1v[((w * 4 + mi) * 8 + kk) * 64 + l];
#pragma unroll
            for (int nt = 0; nt < 4; ++nt) {
                int n = nt * 16 + lo;
                int kb = kk * 32 + hi * 8;
                uint4 bz = *(const uint4*)(&sl[n * 256 + (kb ^ ((n & 15) << 3))]);
#pragma unroll
                for (int mi = 0; mi < 4; ++mi)
                    u[mi][nt] = mfma16(a[mi], bz, u[mi][nt]);
            }
        }
    }
    __syncthreads();
#pragma unroll
    for (int mi = 0; mi < 4; ++mi) {
#pragma unroll
        for (int nt = 0; nt < 4; ++nt) {
            int n = nt * 16 + lo;
            int k0 = (w * 4 + mi) * 16 + hi * 4;
            int col = k0 ^ ((n & 15) << 3);
            float v0 = u[mi][nt][0], v1 = u[mi][nt][1], v2 = u[mi][nt][2], v3 = u[mi][nt][3];
            v0 = v0 > 0.f ? v0 : 0.f; v1 = v1 > 0.f ? v1 : 0.f;
            v2 = v2 > 0.f ? v2 : 0.f; v3 = v3 > 0.f ? v3 : 0.f;
            *(unsigned*)(&sl[n * 256 + col]) = cvt2(v0, v1);
            *(unsigned*)(&sl[n * 256 + col + 2]) = cvt2(v2, v3);
        }
    }
    __syncthreads();

    f32x4 vv[4][4];
#pragma unroll
    for (int mi = 0; mi < 4; ++mi) {
        f32x4 iV;
#pragma unroll
        for (int r = 0; r < 4; ++r) iV[r] = pp2b[(w * 4 + mi) * 16 + hi * 4 + r];
#pragma unroll
        for (int nt = 0; nt < 4; ++nt) vv[mi][nt] = iV;
    }
    {
        const uint4* p2v = (const uint4*)pp2p;
#pragma unroll
        for (int kk = 0; kk < 8; ++kk) {
            uint4 a[4];
#pragma unroll
            for (int mi = 0; mi < 4; ++mi)
                a[mi] = p2v[((w * 4 + mi) * 8 + kk) * 64 + l];
#pragma unroll
            for (int nt = 0; nt < 4; ++nt) {
                int n = nt * 16 + lo;
                int kb = kk * 32 + hi * 8;
                uint4 bz = *(const uint4*)(&sl[n * 256 + (kb ^ ((n & 15) << 3))]);
#pragma unroll
                for (int mi = 0; mi < 4; ++mi)
                    vv[mi][nt] = mfma16(a[mi], bz, vv[mi][nt]);
            }
        }
    }
#pragma unroll
    for (int mi = 0; mi < 4; ++mi) {
#pragma unroll
        for (int nt = 0; nt < 4; ++nt) {
            int t = t0 + nt * 16 + lo;
            int p0 = (w * 4 + mi) * 16 + hi * 4;
#pragma unroll
            for (int r = 0; r < 4; ++r)
                out[((size_t)b * 256 + p0 + r) * T_LEN + t] = vv[mi][nt][r];
        }
    }
}

// ================= launch =================
extern "C" void kernel_launch(void* const* d_in, const int* in_sizes, int n_in,
                              void* d_out, int out_size, void* d_ws, size_t ws_size,
                              hipStream_t stream)
{
    const float* x      = (const float*)d_in[0];
    const float* pre_w  = (const float*)d_in[1];
    const float* pre_b  = (const float*)d_in[2];
    const float* filt_w = (const float*)d_in[3];
    const float* filt_b = (const float*)d_in[4];
    const float* gate_w = (const float*)d_in[5];
    const float* gate_b = (const float*)d_in[6];
    const float* res_w  = (const float*)d_in[7];
    const float* res_b  = (const float*)d_in[8];
    const float* skip_w = (const float*)d_in[9];
    const float* skip_b = (const float*)d_in[10];
    const float* pp1_w  = (const float*)d_in[11];
    const float* pp1_b  = (const float*)d_in[12];
    const float* pp2_w  = (const float*)d_in[13];
    const float* pp2_b  = (const float*)d_in[14];
    float* outp = (float*)d_out;

    // bf16 h ping-pong in d_out (2 x 8.4 MB; final out overwrites all of d_out)
    u16* ht0 = (u16*)outp;
    u16* ht1 = ht0 + (size_t)B_SZ * T_LEN * 64;

    const size_t ZT_BYTES   = (size_t)L_LAYERS * B_SZ * T_LEN * 64 * 2;   // 167,772,160
    const size_t SKIP_BYTES = (size_t)B_SZ * SKIP_C * T_LEN * 4;          // 67,108,864

    const bool useZ = ws_size >= ZT_BYTES + (size_t)2 * 1024 * 1024;

    char* ws = (char*)d_ws;
    u16*   zT      = (u16*)ws;
    float* skipsum = (float*)ws;
    size_t packoff = useZ ? ZT_BYTES : SKIP_BYTES;
    u16* w1p  = (u16*)(ws + packoff);
    u16* swp  = w1p + 327680;
    u16* rwp  = swp + 327680;
    u16* pp1p = rwp + 81920;
    u16* pp2p = pp1p + 65536;
    u16* prep = pp2p + 65536;
    float* sbsum = (float*)(prep + 16384);

    repack2<<<3457, 256, 0, stream>>>(filt_w, gate_w, skip_w, res_w, pp1_w, pp2_w, pre_w, skip_b,
                                      w1p, swp, rwp, pp1p, pp2p, prep, sbsum);

    pre_mfma<<<1024, 256, 0, stream>>>(x, prep, pre_b, ht0);

    const u16* hi_ = ht0; u16* ho_ = ht1;
    for (int i = 0; i < L_LAYERS; ++i) {
        int d = 1 << (i % 10);
        int first = (i == 0) ? 1 : 0;
        int last  = (i == L_LAYERS - 1) ? 1 : 0;
        if (useZ)
            layer_mfma<0><<<1024, 256, 0, stream>>>(
                hi_, ho_,
                zT + (size_t)i * 4194304, skipsum,
                w1p + (size_t)i * 16384, swp + (size_t)i * 16384, rwp + (size_t)i * 4096,
                filt_b + i * 64, gate_b + i * 64, skip_b + i * 256, res_b + i * 64,
                d, first, last);
        else
            layer_mfma<1><<<1024, 256, 0, stream>>>(
                hi_, ho_,
                zT, skipsum,
                w1p + (size_t)i * 16384, swp + (size_t)i * 16384, rwp + (size_t)i * 4096,
                filt_b + i * 64, gate_b + i * 64, skip_b + i * 256, res_b + i * 64,
                d, first, last);
        { const u16* tf = hi_; hi_ = ho_; ho_ = (u16*)tf; }
    }

    if (useZ)
        skip_post<<<1024, 256, 0, stream>>>(zT, swp, sbsum, pp1p, pp1_b, pp2p, pp2_b, outp);
    else
        post_mfma<<<1024, 256, 0, stream>>>(skipsum, pp1p, pp1_b, pp2p, pp2_b, outp);
}